// Round 2
// baseline (278.615 us; speedup 1.0000x reference)
//
#include <hip/hip_runtime.h>
#include <stdint.h>

// RNN: h_{t+1} = tanh(x_t @ W_ih^T + b_ih + b_hh + h_t @ W_hh^T), out = h_T @ fc_w^T + fc_b
// B=8192, T=512, IN=8, H=16.
//
// Mapping (NEW): 32 lanes per batch element = 2 DPP rows of 16 lanes. Lane (r, j)
// owns hidden unit j and computes HALF the recurrent dot product: the 8 terms at
// relative butterfly offsets {8r..8r+7}, plus half the x-projection (x[4r..4r+3]).
// Partials are combined across the row pair with v_permlane16_swap_b32 (gfx950
// full-rate VALU): (p0,p1) = swap(S,S); total = p0+p1. This doubles resident
// waves/SIMD (2 -> 4) for latency hiding and halves the per-stream FMA depth.
//
// Relative-offset split correctness: row 0 gathers sources {j -/+ m : m=0..7}
// (8 consecutive lanes mod 16); row 1 pre-rotates its h-copy by row_ror:8, so its
// sources are the complementary 8 lanes. Union = all 16 units exactly once,
// regardless of the HW rotate direction. Weight pairing is self-calibrated: the
// identical DPP sequence is run on the lane index j at init, giving sv[i] = source
// unit for slot i; weights are loaded pre-permuted.
//
// Algebraic strength reduction: state kept as r = 1/(exp2(S)+1) (h = 1-2r deferred
// into weights): W' = -2c*W_hh (c = 2*log2 e), rowsum(W_hh) folded into bias,
// W_ih and bias pre-scaled by c. The serial chain per step is:
//   ror8 -> cndmask -> 7-mov butterfly -> 3 short FMA chains -> permlane+add
//   -> exp2 -> add -> rcp. No mul before exp2, no tanh-affine fma.
//
// x staging: double-buffered async global_load_lds (16B/lane), one barrier/tile.

#define RNN_B   8192
#define RNN_T   512
#define RNN_IN  8
#define RNN_H   16
#define TC      32                 // timesteps per x tile
#define NE      8                  // batch elements per block (256 thr / 32 lanes)
#define XSTRIDE 264                // padded floats per xs row (256 + 8 pad)
#define NTILE   (RNN_T / TC)
#define BUFSZ   (NE * XSTRIDE)

typedef uint32_t u32x2 __attribute__((ext_vector_type(2)));

// DPP row_ror:N within 16-lane rows (CDNA row = 16 lanes). All lanes active.
#if defined(__has_builtin)
#if __has_builtin(__builtin_amdgcn_mov_dpp)
#define ROR16(x, N) ((uint32_t)__builtin_amdgcn_mov_dpp((int)(x), 0x120 + (N), 0xF, 0xF, false))
#endif
#endif
#ifndef ROR16
#define ROR16(x, N) ((uint32_t)__builtin_amdgcn_update_dpp(0, (int)(x), 0x120 + (N), 0xF, 0xF, false))
#endif

// Half butterfly: u[m] = value at relative rotation offset m (m = 0..7), depth 3.
__device__ __forceinline__ void half_gather(uint32_t vb, uint32_t u[8]) {
    u[0] = vb;
    u[4] = ROR16(vb, 4);
    u[2] = ROR16(vb, 2);
    u[6] = ROR16(u[4], 2);
    u[1] = ROR16(vb, 1);
    u[3] = ROR16(u[2], 1);
    u[5] = ROR16(u[4], 1);
    u[7] = ROR16(u[6], 1);
}

// Cross-row pair sum: lanes [0:15]<->[16:31] and [32:47]<->[48:63].
__device__ __forceinline__ float pair_sum(float s) {
#if defined(__has_builtin) && __has_builtin(__builtin_amdgcn_permlane16_swap)
    u32x2 pr = __builtin_amdgcn_permlane16_swap(__float_as_uint(s), __float_as_uint(s),
                                                false, false);
    return __uint_as_float(pr.x) + __uint_as_float(pr.y);
#else
    return s + __uint_as_float((uint32_t)__shfl_xor((int)__float_as_uint(s), 16));
#endif
}

// Stage one 8-row x 32-timestep x tile into LDS via async global_load_lds.
// Wave wv stages rows 2wv, 2wv+1; each row = 256 floats = 64 lanes x 16B.
__device__ __forceinline__ void stage_tile(const float* __restrict__ x,
                                           float* lds_base, int b0, int t0,
                                           int wv, int lane)
{
#pragma unroll
    for (int p = 0; p < 2; ++p) {
        const int row = 2 * wv + p;
        const float* gp = x + ((size_t)(b0 + row) * RNN_T + t0) * RNN_IN + lane * 4;
        float* lp = lds_base + row * XSTRIDE;
        __builtin_amdgcn_global_load_lds(
            (const __attribute__((address_space(1))) uint32_t*)gp,
            (__attribute__((address_space(3))) uint32_t*)lp,
            16, 0, 0);
    }
}

__global__ __launch_bounds__(256, 4) void rnn_fused_kernel(
    const float* __restrict__ x,     // [B, T, IN]
    const float* __restrict__ W_ih,  // [H, IN]
    const float* __restrict__ W_hh,  // [H, H]
    const float* __restrict__ b_ih,  // [H]
    const float* __restrict__ b_hh,  // [H]
    const float* __restrict__ fc_w,  // [1, H]
    const float* __restrict__ fc_b,  // [1]
    float* __restrict__ out)         // [B, 1]
{
    __shared__ float xs[2 * BUFSZ];  // double-buffered x tiles (16.9 KB)

    const int tid  = (int)threadIdx.x;
    const int j    = tid & 15;           // hidden unit
    const int r    = (tid >> 4) & 1;     // row (K-half) within element
    const int g    = tid >> 5;           // element within block (0..7)
    const int wv   = tid >> 6;           // wave within block
    const int lane = tid & 63;
    const int b0   = (int)blockIdx.x * NE;
    const bool rsel = (r == 1);

    const float C = 2.8853900817779268f;   // 2*log2(e)

    // --- calibrate: run the EXACT runtime DPP sequence on the lane index j.
    // sv[i] = within-row source unit whose state lands in slot i on this lane.
    uint32_t sv[8];
    {
        uint32_t t8 = ROR16((uint32_t)j, 8);
        uint32_t vb = rsel ? t8 : (uint32_t)j;
        half_gather(vb, sv);
    }

    // Per-lane weights, pre-permuted and pre-scaled.
    //   S = c*(bias+rowsumW) [split across rows] + sum_i c*wih*x + sum_i (-2c*whh)*r
    float whh_l[8];
    float rsum = 0.0f;
#pragma unroll
    for (int i = 0; i < 8; ++i) {
        float w = W_hh[j * RNN_H + (int)sv[i]];
        whh_l[i] = -2.0f * C * w;
        rsum += w;
    }
    float bias_l = C * rsum;
    if (!rsel) bias_l += C * (b_ih[j] + b_hh[j]);

    float wih_l[4];
    {
        float4 w = *(const float4*)(W_ih + j * RNN_IN + 4 * r);
        wih_l[0] = C * w.x; wih_l[1] = C * w.y; wih_l[2] = C * w.z; wih_l[3] = C * w.w;
    }

    // prologue: stage tile 0 into buffer 0
    stage_tile(x, xs, b0, 0, wv, lane);
    __syncthreads();   // vmcnt(0) drain + barrier: tile 0 resident

    float rv = 0.5f;   // r-state for h0 = 0  (h = 1 - 2r)

    for (int tile = 0; tile < NTILE; ++tile) {
        const int cur = tile & 1;
        if (tile + 1 < NTILE)
            stage_tile(x, xs + (cur ^ 1) * BUFSZ, b0, (tile + 1) * TC, wv, lane);

        // per-lane x pointer: element row g, this row's 4 input features
        const float* xg = xs + cur * BUFSZ + g * XSTRIDE + 4 * r;

#pragma unroll 8
        for (int tt = 0; tt < TC; ++tt) {
            const float4 xv = *(const float4*)(xg + tt * RNN_IN);  // 16-lane broadcast

            // row 1 pre-rotates its state copy by 8 so both rows use offsets 0..7
            const uint32_t rb = __float_as_uint(rv);
            const uint32_t t8 = ROR16(rb, 8);
            const uint32_t vb = rsel ? t8 : rb;
            uint32_t u[8];
            half_gather(vb, u);

            // 3 short independent chains
            float c0 = fmaf(wih_l[0], xv.x, bias_l);
            c0 = fmaf(wih_l[1], xv.y, c0);
            c0 = fmaf(wih_l[2], xv.z, c0);
            c0 = fmaf(wih_l[3], xv.w, c0);

            float c1 = whh_l[0] * __uint_as_float(u[0]);
            c1 = fmaf(whh_l[1], __uint_as_float(u[1]), c1);
            c1 = fmaf(whh_l[2], __uint_as_float(u[2]), c1);
            c1 = fmaf(whh_l[3], __uint_as_float(u[3]), c1);

            float c2 = whh_l[4] * __uint_as_float(u[4]);
            c2 = fmaf(whh_l[5], __uint_as_float(u[5]), c2);
            c2 = fmaf(whh_l[6], __uint_as_float(u[6]), c2);
            c2 = fmaf(whh_l[7], __uint_as_float(u[7]), c2);

            const float sp   = (c0 + c1) + c2;      // this row's partial
            const float stot = pair_sum(sp);        // full pre-activation (scaled)

            // r = 1/(exp2(S)+1); saturates correctly at +/-inf
            const float e = __builtin_amdgcn_exp2f(stot);
            rv = __builtin_amdgcn_rcpf(e + 1.0f);
        }
        __syncthreads();   // drains next-tile loads (issued a tile ago) + sync
    }

    // --- epilogue: h = 1 - 2r; out[b] = sum_j fc_w[j]*h_j + fc_b (both rows
    // hold identical h; reduce within each 16-lane row, row masks the write) ---
    const float h = fmaf(-2.0f, rv, 1.0f);
    float vsum = h * fc_w[j];
    vsum += __shfl_xor(vsum, 1);
    vsum += __shfl_xor(vsum, 2);
    vsum += __shfl_xor(vsum, 4);
    vsum += __shfl_xor(vsum, 8);
    if ((tid & 31) == 0) out[b0 + g] = vsum + fc_b[0];
}

extern "C" void kernel_launch(void* const* d_in, const int* in_sizes, int n_in,
                              void* d_out, int out_size, void* d_ws, size_t ws_size,
                              hipStream_t stream)
{
    const float* x    = (const float*)d_in[0];
    const float* W_ih = (const float*)d_in[1];
    const float* W_hh = (const float*)d_in[2];
    const float* b_ih = (const float*)d_in[3];
    const float* b_hh = (const float*)d_in[4];
    const float* fc_w = (const float*)d_in[5];
    const float* fc_b = (const float*)d_in[6];
    float* out = (float*)d_out;

    dim3 grid(RNN_B / NE);   // 1024 blocks = 4 blocks/CU = 4 waves/SIMD
    dim3 block(256);
    rnn_fused_kernel<<<grid, block, 0, stream>>>(x, W_ih, W_hh, b_ih, b_hh, fc_w, fc_b, out);
}

// Round 4
// 266.599 us; speedup vs baseline: 1.0451x; 1.0451x over previous
//
#include <hip/hip_runtime.h>
#include <stdint.h>

// RNN: h_{t+1} = tanh(x_t @ W_ih^T + b_ih + b_hh + h_t @ W_hh^T), out = h_T @ fc_w^T + fc_b
// B=8192, T=512, IN=8, H=16.
//
// MFMA formulation: one wave owns 16 batch elements; each step is
//   D[unit][elem] = A.B + C  via 2x mfma_f32_16x16x32_f16 (K=32 slots):
//   MFMA1: A1 = [Vhi | Vhi],          B1 = [r_hi(16) | r_lo(16)]
//   MFMA2: A2 = [Vlo | Uhi | Ulo],    B2 = [r_hi(16) | x(8) | x(8)]
// where V = -2c*W_hh, U = c*W_ih (c = 2*log2 e), split into fp16 hi + fp16 lo
// residuals; state kept as r = 1/(exp2(c*s)+1), h = 1-2r folded into V and the
// bias C (rowsum trick, proven in rounds 0-2). This compensates fp16 to ~2^-22
// except the (small) Wih*x_lo term.
//
// Layout trick: computing H^T = W*H^T makes the D fragment (col=lane&15=elem,
// row=(lane>>4)*4+reg=unit) line up with the B fragment (n=lane&15, k=(lane>>4)*8+i),
// so the only cross-lane movement per step is ds_bpermute(lane^32) on the packed
// state (4 ops) + quarter-selects (8 cndmask). A-fragment k-columns are assigned
// to match exactly what lands in each B slot.
//
// Mapping: 64-thread (1-wave) blocks, 512 blocks (2/CU). x staged to LDS with
// double-buffered async global_load_lds; __syncthreads() per tile is the fence.
//
// FIX vs round 3: use __fp16 ext-vectors throughout (clang's 'h' type) — the
// cvt_pkrtz and mfma f16 builtins are declared with __fp16 vectors, and
// _Float16 vectors are treated as incompatible.

#define RNN_B   8192
#define RNN_T   512
#define RNN_IN  8
#define RNN_H   16
#define TC      32                  // timesteps per x tile
#define NE      16                  // batch elements per block (= per wave)
#define XROW    260                 // floats per staged row (TC*8=256 +4 pad)
#define NTILE   (RNN_T / TC)
#define BUFSZ   (NE * XROW)

typedef __fp16 half8  __attribute__((ext_vector_type(8)));
typedef __fp16 half2v __attribute__((ext_vector_type(2)));
typedef float  f32x4  __attribute__((ext_vector_type(4)));

union H8U { half8 v; __fp16 e[8]; uint32_t u[4]; };
union H2U { half2v h; uint32_t u; };

static __device__ __forceinline__ uint32_t pkh(float a, float b) {
    H2U t; t.h = __builtin_amdgcn_cvt_pkrtz(a, b); return t.u;
}
static __device__ __forceinline__ uint32_t bp32(int addr, uint32_t v) {
    return (uint32_t)__builtin_amdgcn_ds_bpermute(addr, (int)v);
}

// Stage one 16-elem x 32-timestep x tile: each row = 256 floats = 1024 B =
// exactly one global_load_lds (64 lanes x 16 B), wave-uniform LDS base per row.
static __device__ __forceinline__ void stage(const float* __restrict__ x,
                                             float* lds_base, int b0, int t0,
                                             int lane)
{
#pragma unroll
    for (int e = 0; e < NE; ++e) {
        const float* gp = x + ((size_t)(b0 + e) * RNN_T + t0) * RNN_IN + lane * 4;
        float* lp = lds_base + e * XROW;
        __builtin_amdgcn_global_load_lds(
            (const __attribute__((address_space(1))) uint32_t*)gp,
            (__attribute__((address_space(3))) uint32_t*)lp,
            16, 0, 0);
    }
}

__global__ __launch_bounds__(64) void rnn_mfma_kernel(
    const float* __restrict__ x,     // [B, T, IN]
    const float* __restrict__ W_ih,  // [H, IN]
    const float* __restrict__ W_hh,  // [H, H]
    const float* __restrict__ b_ih,  // [H]
    const float* __restrict__ b_hh,  // [H]
    const float* __restrict__ fc_w,  // [1, H]
    const float* __restrict__ fc_b,  // [1]
    float* __restrict__ out)         // [B, 1]
{
    __shared__ __align__(16) float xs[2 * BUFSZ];   // 33.3 KB double-buffered x

    const int lane = (int)threadIdx.x;   // 0..63
    const int col  = lane & 15;          // elem (B/D col) AND unit row m (A)
    const int q    = lane >> 4;          // lane quarter = k-slot group
    const int b0   = (int)blockIdx.x * NE;
    const bool hi32  = (lane & 32) != 0;
    const int addr32 = (lane ^ 32) << 2; // ds_bpermute byte index (keeps col, flips q^2)
    const float C2 = 2.8853900817779268f;   // 2*log2(e)

    // ---- A fragments.  A[m][k]: m = lane&15, k = q*8 + j (j=0..7, f16 pair order).
    // B slot content (by construction below): reg i holds, at quarter q:
    //   i<2  -> own D pairs  = units (4q+2i, 4q+2i+1)
    //   i>=2 -> bp32 partner = units (4(q^2)+2(i-2), +1)
    // so unit(q,j) = 4*((j>>1)<2 ? q : q^2) + 2*((j>>1)&1) + (j&1), for both the
    // hi slots (q=0,1) and the lo slots (q=2,3).  MFMA2's q=2,3 slots carry x.
    H8U A1, A2;
#pragma unroll
    for (int j = 0; j < 8; ++j) {
        const int i = j >> 1, hb = j & 1;
        const int u = 4 * ((i < 2) ? q : (q ^ 2)) + 2 * (i & 1) + hb;
        const float v = -2.0f * C2 * W_hh[col * RNN_H + u];
        const __fp16 vh = (__fp16)v;
        A1.e[j] = vh;                              // Vhi (multiplies r_hi and r_lo)
        if (q < 2) A2.e[j] = (__fp16)(v - (float)vh);   // Vlo (multiplies r_hi)
    }
    if (q >= 2) {
#pragma unroll
        for (int j = 0; j < 8; ++j) {
            const float uu = C2 * W_ih[col * RNN_IN + j];
            const __fp16 uh = (__fp16)uu;
            A2.e[j] = (q == 2) ? uh : (__fp16)(uu - (float)uh);  // Uhi / Ulo
        }
    }

    // ---- C bias fragment: D rows = units 4q+rr.  cb = c*(b_ih+b_hh) + c*rowsum(Weff)
    // with Weff = -(Vhi+Vlo)/(2c) — exact consistency with the h = 1-2r fold.
    f32x4 cb;
#pragma unroll
    for (int rr = 0; rr < 4; ++rr) {
        const int u = 4 * q + rr;
        float s = 0.0f;
        for (int k = 0; k < RNN_H; ++k) {
            const float v = -2.0f * C2 * W_hh[u * RNN_H + k];
            const __fp16 vh = (__fp16)v;
            const __fp16 vl = (__fp16)(v - (float)vh);
            s += (float)vh + (float)vl;
        }
        cb[rr] = C2 * (b_ih[u] + b_hh[u]) - 0.5f * s;
    }

    // prologue: tile 0 -> buffer 0
    stage(x, xs, b0, 0, lane);
    __syncthreads();

    // state: r = 0.5 (h0 = 0); fp16(0.5) exact -> lo = 0
    uint32_t rh0 = pkh(0.5f, 0.5f), rh1 = pkh(0.5f, 0.5f);
    uint32_t rl0 = 0u, rl1 = 0u;

    for (int tile = 0; tile < NTILE; ++tile) {
        const int cur = tile & 1;
        if (tile + 1 < NTILE)
            stage(x, xs + (cur ^ 1) * BUFSZ, b0, (tile + 1) * TC, lane);

        const float* xg = xs + cur * BUFSZ + col * XROW;

#pragma unroll 4
        for (int tt = 0; tt < TC; ++tt) {
            // x for elem `col`, feats 0..7 (same addr across quarters: LDS broadcast)
            const float4 xa = *(const float4*)(xg + tt * 8);
            const float4 xb = *(const float4*)(xg + tt * 8 + 4);
            const uint32_t xh0 = pkh(xa.x, xa.y), xh1 = pkh(xa.z, xa.w);
            const uint32_t xh2 = pkh(xb.x, xb.y), xh3 = pkh(xb.z, xb.w);

            // cross-half-wave state exchange (keeps col, swaps quarter q <-> q^2)
            const uint32_t G0h = bp32(addr32, rh0), G1h = bp32(addr32, rh1);
            const uint32_t G0l = bp32(addr32, rl0), G1l = bp32(addr32, rl1);

            H8U B1, B2;
            B1.u[0] = hi32 ? rl0 : rh0;  B1.u[1] = hi32 ? rl1 : rh1;
            B1.u[2] = hi32 ? G0l : G0h;  B1.u[3] = hi32 ? G1l : G1h;
            B2.u[0] = hi32 ? xh0 : rh0;  B2.u[1] = hi32 ? xh1 : rh1;
            B2.u[2] = hi32 ? xh2 : G0h;  B2.u[3] = hi32 ? xh3 : G1h;

            f32x4 acc = __builtin_amdgcn_mfma_f32_16x16x32_f16(A1.v, B1.v, cb, 0, 0, 0);
            acc = __builtin_amdgcn_mfma_f32_16x16x32_f16(A2.v, B2.v, acc, 0, 0, 0);

            // r = 1/(exp2(S)+1), S pre-scaled by c; saturates correctly at +/-inf
            const float r0 = __builtin_amdgcn_rcpf(__builtin_amdgcn_exp2f(acc[0]) + 1.0f);
            const float r1 = __builtin_amdgcn_rcpf(__builtin_amdgcn_exp2f(acc[1]) + 1.0f);
            const float r2 = __builtin_amdgcn_rcpf(__builtin_amdgcn_exp2f(acc[2]) + 1.0f);
            const float r3 = __builtin_amdgcn_rcpf(__builtin_amdgcn_exp2f(acc[3]) + 1.0f);

            // hi/lo split of the state (residual compensation)
            rh0 = pkh(r0, r1); rh1 = pkh(r2, r3);
            H2U u0, u1; u0.u = rh0; u1.u = rh1;
            rl0 = pkh(r0 - (float)u0.h[0], r1 - (float)u0.h[1]);
            rl1 = pkh(r2 - (float)u1.h[0], r3 - (float)u1.h[1]);
        }
        __syncthreads();   // drains next-tile global_load_lds + fences LDS reads
    }

    // ---- epilogue: h = 1 - 2(r_hi + r_lo); out[elem] = sum_u fc_w[u]*h_u + fc_b
    H2U a0, a1, c0, c1;
    a0.u = rh0; a1.u = rh1; c0.u = rl0; c1.u = rl1;
    const float h0 = 1.0f - 2.0f * ((float)a0.h[0] + (float)c0.h[0]);
    const float h1 = 1.0f - 2.0f * ((float)a0.h[1] + (float)c0.h[1]);
    const float h2 = 1.0f - 2.0f * ((float)a1.h[0] + (float)c1.h[0]);
    const float h3 = 1.0f - 2.0f * ((float)a1.h[1] + (float)c1.h[1]);
    float p = fc_w[4 * q + 0] * h0 + fc_w[4 * q + 1] * h1
            + fc_w[4 * q + 2] * h2 + fc_w[4 * q + 3] * h3;
    p += __shfl_xor(p, 16);
    p += __shfl_xor(p, 32);
    if (lane < 16) out[b0 + col] = p + fc_b[0];
}

extern "C" void kernel_launch(void* const* d_in, const int* in_sizes, int n_in,
                              void* d_out, int out_size, void* d_ws, size_t ws_size,
                              hipStream_t stream)
{
    const float* x    = (const float*)d_in[0];
    const float* W_ih = (const float*)d_in[1];
    const float* W_hh = (const float*)d_in[2];
    const float* b_ih = (const float*)d_in[3];
    const float* b_hh = (const float*)d_in[4];
    const float* fc_w = (const float*)d_in[5];
    const float* fc_b = (const float*)d_in[6];
    float* out = (float*)d_out;

    dim3 grid(RNN_B / NE);   // 512 blocks x 64 threads = 2 waves/CU
    dim3 block(64);
    rnn_mfma_kernel<<<grid, block, 0, stream>>>(x, W_ih, W_hh, b_ih, b_hh, fc_w, fc_b, out);
}

// Round 5
// 233.837 us; speedup vs baseline: 1.1915x; 1.1401x over previous
//
#include <hip/hip_runtime.h>
#include <stdint.h>

// RNN: h_{t+1} = tanh(x_t @ W_ih^T + b_ih + b_hh + h_t @ W_hh^T), out = h_T @ fc_w^T + fc_b
// B=8192, T=512, IN=8, H=16.
//
// MFMA formulation, ZERO cross-lane state movement. One wave owns 16 elements;
// per step, D[unit][elem] = A.B + C via 2 INDEPENDENT mfma_f32_16x16x32_f16:
//
//   quarter q (lane>>4) holds D units 4q..4q+3 for elem n = lane&15, and supplies
//   B k-slots 8q..8q+7 for the SAME elem. So each quarter feeds its own units'
//   state straight from the previous D fragment into B — the MFMA's internal
//   K-reduction does the cross-lane sum. No bpermute, no cndmask.
//
//   MFMA1: B1 = {rh0,rh1,rh0,rh1}   A1.e[j] = Vhi[col][4q+(j&3)] (j<4), Vlo (j>=4)
//   MFMA2: B2 = {rl0,rl1,xq,xq}     A2.e[j] = Vhi[col][4q+j] (j<4),
//                                            Uhi[col][2q+(j-4)] (j=4,5),
//                                            Ulo[col][2q+(j-6)] (j=6,7)
//   (V = -2c*W_hh, U = c*W_ih, c = 2*log2 e, hi/lo fp16 residual split; state is
//    r = 1/(exp2(c*s)+1), tanh affine folded into V and the bias C. Dropped terms:
//    Vlo*r_lo (~2^-22) and x_lo (same as round 4's passing numerics).)
//
// The two MFMAs accumulate separately (cb and 0) and are summed by 4 independent
// v_add -> they overlap instead of serializing through the accumulator.
// Serial chain per step: pk(r) -> MFMA -> add -> exp2 -> add -> rcp -> pk.
// x feed: one ds_read_b64 + one cvt_pkrtz per lane per step, state-independent
// (prefetched across the unroll).
//
// Mapping: 64-thread blocks, 512 blocks (all streams parallel; time = T x chain).
// x staged to LDS with double-buffered async global_load_lds, 1 barrier/tile.

#define RNN_B   8192
#define RNN_T   512
#define RNN_IN  8
#define RNN_H   16
#define TC      32                  // timesteps per x tile
#define NE      16                  // batch elements per block (= per wave)
#define XROW    260                 // floats per staged row (256 + 4 pad; 16B-aligned rows)
#define NTILE   (RNN_T / TC)
#define BUFSZ   (NE * XROW)

typedef __fp16 half8  __attribute__((ext_vector_type(8)));
typedef __fp16 half2v __attribute__((ext_vector_type(2)));
typedef float  f32x4  __attribute__((ext_vector_type(4)));

union H8U { half8 v; __fp16 e[8]; uint32_t u[4]; };
union H2U { half2v h; uint32_t u; };

static __device__ __forceinline__ uint32_t pkh(float a, float b) {
    H2U t; t.h = __builtin_amdgcn_cvt_pkrtz(a, b); return t.u;
}

// Stage one 16-elem x 32-timestep x tile: each row = 256 floats = 1024 B =
// exactly one global_load_lds (64 lanes x 16 B), wave-uniform LDS base per row.
static __device__ __forceinline__ void stage(const float* __restrict__ x,
                                             float* lds_base, int b0, int t0,
                                             int lane)
{
#pragma unroll
    for (int e = 0; e < NE; ++e) {
        const float* gp = x + ((size_t)(b0 + e) * RNN_T + t0) * RNN_IN + lane * 4;
        float* lp = lds_base + e * XROW;
        __builtin_amdgcn_global_load_lds(
            (const __attribute__((address_space(1))) uint32_t*)gp,
            (__attribute__((address_space(3))) uint32_t*)lp,
            16, 0, 0);
    }
}

__global__ __launch_bounds__(64) void rnn_mfma_kernel(
    const float* __restrict__ x,     // [B, T, IN]
    const float* __restrict__ W_ih,  // [H, IN]
    const float* __restrict__ W_hh,  // [H, H]
    const float* __restrict__ b_ih,  // [H]
    const float* __restrict__ b_hh,  // [H]
    const float* __restrict__ fc_w,  // [1, H]
    const float* __restrict__ fc_b,  // [1]
    float* __restrict__ out)         // [B, 1]
{
    __shared__ __align__(16) float xs[2 * BUFSZ];   // 33.3 KB double-buffered x

    const int lane = (int)threadIdx.x;   // 0..63
    const int col  = lane & 15;          // elem (B/D col) AND A-row (output unit m)
    const int q    = lane >> 4;          // lane quarter: owns D units 4q..4q+3
    const int b0   = (int)blockIdx.x * NE;
    const float C2 = 2.8853900817779268f;   // 2*log2(e)

    // ---- A fragments (per-lane k-columns chosen to match what each quarter's
    // B slots carry; see header).
    H8U A1, A2;
#pragma unroll
    for (int j = 0; j < 4; ++j) {
        const int u = 4 * q + j;
        const float v = -2.0f * C2 * W_hh[col * RNN_H + u];
        const __fp16 vh = (__fp16)v;
        const __fp16 vl = (__fp16)(v - (float)vh);
        A1.e[j]     = vh;   // x rh
        A1.e[j + 4] = vl;   // x rh (second copy of rh in slots 4..7)
        A2.e[j]     = vh;   // x rl
    }
#pragma unroll
    for (int j = 0; j < 2; ++j) {
        const int f = 2 * q + j;
        const float uu = C2 * W_ih[col * RNN_IN + f];
        const __fp16 uh = (__fp16)uu;
        A2.e[4 + j] = uh;                        // Uhi x x
        A2.e[6 + j] = (__fp16)(uu - (float)uh);  // Ulo x x
    }

    // ---- C bias fragment: D rows = units 4q+rr.
    // cb = c*(b_ih+b_hh) - 0.5*rowsum(Vhi+Vlo)  (exact h=1-2r fold consistency)
    f32x4 cb;
#pragma unroll
    for (int rr = 0; rr < 4; ++rr) {
        const int u = 4 * q + rr;
        float s = 0.0f;
        for (int k = 0; k < RNN_H; ++k) {
            const float v = -2.0f * C2 * W_hh[u * RNN_H + k];
            const __fp16 vh = (__fp16)v;
            const __fp16 vl = (__fp16)(v - (float)vh);
            s += (float)vh + (float)vl;
        }
        cb[rr] = C2 * (b_ih[u] + b_hh[u]) - 0.5f * s;
    }
    const f32x4 zero4 = {0.0f, 0.0f, 0.0f, 0.0f};

    // prologue: tile 0 -> buffer 0
    stage(x, xs, b0, 0, lane);
    __syncthreads();

    // state r = 0.5 (h0 = 0); fp16(0.5) exact -> lo residual = 0
    uint32_t rh0 = pkh(0.5f, 0.5f), rh1 = pkh(0.5f, 0.5f);
    uint32_t rl0 = 0u, rl1 = 0u;

    for (int tile = 0; tile < NTILE; ++tile) {
        const int cur = tile & 1;
        if (tile + 1 < NTILE)
            stage(x, xs + (cur ^ 1) * BUFSZ, b0, (tile + 1) * TC, lane);

        // per-lane x pointer: elem col, features 2q, 2q+1
        const float* xg = xs + cur * BUFSZ + col * XROW + 2 * q;

#pragma unroll 8
        for (int tt = 0; tt < TC; ++tt) {
            // x feed (state-independent; prefetched by the scheduler)
            const float2 xf = *(const float2*)(xg + tt * 8);
            const uint32_t xq = pkh(xf.x, xf.y);

            H8U B1, B2;
            B1.u[0] = rh0; B1.u[1] = rh1; B1.u[2] = rh0; B1.u[3] = rh1;
            B2.u[0] = rl0; B2.u[1] = rl1; B2.u[2] = xq;  B2.u[3] = xq;

            // two independent MFMAs (overlapping latencies), summed below
            const f32x4 ac1 = __builtin_amdgcn_mfma_f32_16x16x32_f16(A1.v, B1.v, cb,    0, 0, 0);
            const f32x4 ac2 = __builtin_amdgcn_mfma_f32_16x16x32_f16(A2.v, B2.v, zero4, 0, 0, 0);

            // r = 1/(exp2(S)+1), S pre-scaled by c; per-element independent chains
            const float r0 = __builtin_amdgcn_rcpf(__builtin_amdgcn_exp2f(ac1[0] + ac2[0]) + 1.0f);
            const float r1 = __builtin_amdgcn_rcpf(__builtin_amdgcn_exp2f(ac1[1] + ac2[1]) + 1.0f);
            const float r2 = __builtin_amdgcn_rcpf(__builtin_amdgcn_exp2f(ac1[2] + ac2[2]) + 1.0f);
            const float r3 = __builtin_amdgcn_rcpf(__builtin_amdgcn_exp2f(ac1[3] + ac2[3]) + 1.0f);

            // hi/lo split of the state (residual compensation).
            // rh is on the MFMA1 chain; rl hides under MFMA1's latency next step.
            rh0 = pkh(r0, r1); rh1 = pkh(r2, r3);
            H2U u0, u1; u0.u = rh0; u1.u = rh1;
            rl0 = pkh(r0 - (float)u0.h[0], r1 - (float)u0.h[1]);
            rl1 = pkh(r2 - (float)u1.h[0], r3 - (float)u1.h[1]);
        }
        __syncthreads();   // drains next-tile global_load_lds + fences LDS reads
    }

    // ---- epilogue: h = 1 - 2(r_hi + r_lo); out[elem] = sum_u fc_w[u]*h_u + fc_b
    H2U a0, a1, c0, c1;
    a0.u = rh0; a1.u = rh1; c0.u = rl0; c1.u = rl1;
    const float h0 = 1.0f - 2.0f * ((float)a0.h[0] + (float)c0.h[0]);
    const float h1 = 1.0f - 2.0f * ((float)a0.h[1] + (float)c0.h[1]);
    const float h2 = 1.0f - 2.0f * ((float)a1.h[0] + (float)c1.h[0]);
    const float h3 = 1.0f - 2.0f * ((float)a1.h[1] + (float)c1.h[1]);
    float p = fc_w[4 * q + 0] * h0 + fc_w[4 * q + 1] * h1
            + fc_w[4 * q + 2] * h2 + fc_w[4 * q + 3] * h3;
    p += __shfl_xor(p, 16);
    p += __shfl_xor(p, 32);
    if (lane < 16) out[b0 + col] = p + fc_b[0];
}

extern "C" void kernel_launch(void* const* d_in, const int* in_sizes, int n_in,
                              void* d_out, int out_size, void* d_ws, size_t ws_size,
                              hipStream_t stream)
{
    const float* x    = (const float*)d_in[0];
    const float* W_ih = (const float*)d_in[1];
    const float* W_hh = (const float*)d_in[2];
    const float* b_ih = (const float*)d_in[3];
    const float* b_hh = (const float*)d_in[4];
    const float* fc_w = (const float*)d_in[5];
    const float* fc_b = (const float*)d_in[6];
    float* out = (float*)d_out;

    dim3 grid(RNN_B / NE);   // 512 blocks x 64 threads
    dim3 block(64);
    rnn_mfma_kernel<<<grid, block, 0, stream>>>(x, W_ih, W_hh, b_ih, b_hh, fc_w, fc_b, out);
}

// Round 6
// 224.496 us; speedup vs baseline: 1.2411x; 1.0416x over previous
//
#include <hip/hip_runtime.h>
#include <stdint.h>

// RNN: h_{t+1} = tanh(x_t @ W_ih^T + b_ih + b_hh + h_t @ W_hh^T), out = h_T @ fc_w^T + fc_b
// B=8192, T=512, IN=8, H=16.
//
// MFMA formulation, ZERO cross-lane state movement (round-5 structure). One wave
// owns 16 elements; per step, D[unit][elem] = A.B + C via 2 INDEPENDENT
// mfma_f32_16x16x32_f16; quarter q feeds its own units' state straight from the
// previous D fragment into its B k-slots (the MFMA's internal K-reduction does the
// cross-lane sum). V = -2c*W_hh, U = c*W_ih (c = 2*log2 e), fp16 hi/lo residual
// compensation; state r = 1/(exp2(c*s)+1), tanh affine folded into V and bias.
//
// CHANGE vs round 5 (chain-latency attack): x is PREFETCHED INTO REGISTERS per
// tile (32x ds_read_b64 + cvt_pkrtz -> xq[32], fully unrolled => static reg
// indexing). The inner 32-step loop is pure register work; no LDS op, no lgkm/vmem
// wait can land on the recurrence chain. Prefetch reads are issued BEFORE the next
// tile's global_load_lds so the compiler cannot order an async-LDS-write fence in
// front of them. Evidence: round-5's per-step ds_read put ~1M bank-conflict cycles
// and an LDS round-trip (~120cyc, m117) inside every step -> 420 cyc/step measured.
//
// Mapping: 64-thread blocks, 512 blocks (all 512 chains run in parallel; wall time
// = T x per-step chain latency). x staged to LDS double-buffered, 1 barrier/tile.

#define RNN_B   8192
#define RNN_T   512
#define RNN_IN  8
#define RNN_H   16
#define TC      32                  // timesteps per x tile
#define NE      16                  // batch elements per block (= per wave)
#define XROW    260                 // floats per staged row (256 + 4 pad; 1040B = 16B-aligned)
#define NTILE   (RNN_T / TC)
#define BUFSZ   (NE * XROW)

typedef __fp16 half8  __attribute__((ext_vector_type(8)));
typedef __fp16 half2v __attribute__((ext_vector_type(2)));
typedef float  f32x4  __attribute__((ext_vector_type(4)));

union H8U { half8 v; __fp16 e[8]; uint32_t u[4]; };
union H2U { half2v h; uint32_t u; };

static __device__ __forceinline__ uint32_t pkh(float a, float b) {
    H2U t; t.h = __builtin_amdgcn_cvt_pkrtz(a, b); return t.u;
}

// Stage one 16-elem x 32-timestep x tile: each row = 256 floats = 1024 B =
// exactly one global_load_lds (64 lanes x 16 B), wave-uniform LDS base per row.
static __device__ __forceinline__ void stage(const float* __restrict__ x,
                                             float* lds_base, int b0, int t0,
                                             int lane)
{
#pragma unroll
    for (int e = 0; e < NE; ++e) {
        const float* gp = x + ((size_t)(b0 + e) * RNN_T + t0) * RNN_IN + lane * 4;
        float* lp = lds_base + e * XROW;
        __builtin_amdgcn_global_load_lds(
            (const __attribute__((address_space(1))) uint32_t*)gp,
            (__attribute__((address_space(3))) uint32_t*)lp,
            16, 0, 0);
    }
}

__global__ __launch_bounds__(64) void rnn_mfma_kernel(
    const float* __restrict__ x,     // [B, T, IN]
    const float* __restrict__ W_ih,  // [H, IN]
    const float* __restrict__ W_hh,  // [H, H]
    const float* __restrict__ b_ih,  // [H]
    const float* __restrict__ b_hh,  // [H]
    const float* __restrict__ fc_w,  // [1, H]
    const float* __restrict__ fc_b,  // [1]
    float* __restrict__ out)         // [B, 1]
{
    __shared__ __align__(16) float xs[2 * BUFSZ];   // 33.3 KB double-buffered x

    const int lane = (int)threadIdx.x;   // 0..63
    const int col  = lane & 15;          // elem (B/D col) AND A-row (output unit m)
    const int q    = lane >> 4;          // lane quarter: owns D units 4q..4q+3
    const int b0   = (int)blockIdx.x * NE;
    const float C2 = 2.8853900817779268f;   // 2*log2(e)

    // ---- A fragments (k-columns match what each quarter's B slots carry).
    H8U A1, A2;
#pragma unroll
    for (int j = 0; j < 4; ++j) {
        const int u = 4 * q + j;
        const float v = -2.0f * C2 * W_hh[col * RNN_H + u];
        const __fp16 vh = (__fp16)v;
        const __fp16 vl = (__fp16)(v - (float)vh);
        A1.e[j]     = vh;   // x rh (slots 0..3)
        A1.e[j + 4] = vl;   // x rh (slots 4..7: second copy of rh)
        A2.e[j]     = vh;   // x rl
    }
#pragma unroll
    for (int j = 0; j < 2; ++j) {
        const int f = 2 * q + j;
        const float uu = C2 * W_ih[col * RNN_IN + f];
        const __fp16 uh = (__fp16)uu;
        A2.e[4 + j] = uh;                        // Uhi x x
        A2.e[6 + j] = (__fp16)(uu - (float)uh);  // Ulo x x
    }

    // ---- C bias fragment: D rows = units 4q+rr.
    // cb = c*(b_ih+b_hh) - 0.5*rowsum(Vhi+Vlo)  (exact h=1-2r fold consistency)
    f32x4 cb;
#pragma unroll
    for (int rr = 0; rr < 4; ++rr) {
        const int u = 4 * q + rr;
        float s = 0.0f;
        for (int k = 0; k < RNN_H; ++k) {
            const float v = -2.0f * C2 * W_hh[u * RNN_H + k];
            const __fp16 vh = (__fp16)v;
            const __fp16 vl = (__fp16)(v - (float)vh);
            s += (float)vh + (float)vl;
        }
        cb[rr] = C2 * (b_ih[u] + b_hh[u]) - 0.5f * s;
    }
    const f32x4 zero4 = {0.0f, 0.0f, 0.0f, 0.0f};

    // prologue: tile 0 -> buffer 0
    stage(x, xs, b0, 0, lane);
    __syncthreads();

    // state r = 0.5 (h0 = 0); fp16(0.5) exact -> lo residual = 0
    uint32_t rh0 = pkh(0.5f, 0.5f), rh1 = pkh(0.5f, 0.5f);
    uint32_t rl0 = 0u, rl1 = 0u;

    for (int tile = 0; tile < NTILE; ++tile) {
        const int cur = tile & 1;

        // ---- x prefetch: whole tile into registers (off the recurrence chain).
        // Issued BEFORE next tile's global_load_lds so no vmem-ordering wait can
        // precede these ds_reads. Fully unrolled => xq[] stays in registers.
        const float* xg = xs + cur * BUFSZ + col * XROW + 2 * q;
        uint32_t xq[TC];
#pragma unroll
        for (int tt = 0; tt < TC; ++tt) {
            const float2 xf = *(const float2*)(xg + tt * 8);
            xq[tt] = pkh(xf.x, xf.y);
        }

        // issue next tile's async staging; drained by the end-of-tile barrier
        if (tile + 1 < NTILE)
            stage(x, xs + (cur ^ 1) * BUFSZ, b0, (tile + 1) * TC, lane);

        // ---- 32 pure-register recurrence steps
#pragma unroll
        for (int tt = 0; tt < TC; ++tt) {
            H8U B1, B2;
            B1.u[0] = rh0; B1.u[1] = rh1; B1.u[2] = rh0;    B1.u[3] = rh1;
            B2.u[0] = rl0; B2.u[1] = rl1; B2.u[2] = xq[tt]; B2.u[3] = xq[tt];

            // two independent MFMAs (overlapping latencies), summed below
            const f32x4 ac1 = __builtin_amdgcn_mfma_f32_16x16x32_f16(A1.v, B1.v, cb,    0, 0, 0);
            const f32x4 ac2 = __builtin_amdgcn_mfma_f32_16x16x32_f16(A2.v, B2.v, zero4, 0, 0, 0);

            // r = 1/(exp2(S)+1), S pre-scaled by c; per-element independent chains
            const float r0 = __builtin_amdgcn_rcpf(__builtin_amdgcn_exp2f(ac1[0] + ac2[0]) + 1.0f);
            const float r1 = __builtin_amdgcn_rcpf(__builtin_amdgcn_exp2f(ac1[1] + ac2[1]) + 1.0f);
            const float r2 = __builtin_amdgcn_rcpf(__builtin_amdgcn_exp2f(ac1[2] + ac2[2]) + 1.0f);
            const float r3 = __builtin_amdgcn_rcpf(__builtin_amdgcn_exp2f(ac1[3] + ac2[3]) + 1.0f);

            // hi/lo split of the state (residual compensation)
            rh0 = pkh(r0, r1); rh1 = pkh(r2, r3);
            H2U u0, u1; u0.u = rh0; u1.u = rh1;
            rl0 = pkh(r0 - (float)u0.h[0], r1 - (float)u0.h[1]);
            rl1 = pkh(r2 - (float)u1.h[0], r3 - (float)u1.h[1]);
        }
        __syncthreads();   // drains next-tile global_load_lds + fences LDS reuse
    }

    // ---- epilogue: h = 1 - 2(r_hi + r_lo); out[elem] = sum_u fc_w[u]*h_u + fc_b
    H2U a0, a1, c0, c1;
    a0.u = rh0; a1.u = rh1; c0.u = rl0; c1.u = rl1;
    const float h0 = 1.0f - 2.0f * ((float)a0.h[0] + (float)c0.h[0]);
    const float h1 = 1.0f - 2.0f * ((float)a0.h[1] + (float)c0.h[1]);
    const float h2 = 1.0f - 2.0f * ((float)a1.h[0] + (float)c1.h[0]);
    const float h3 = 1.0f - 2.0f * ((float)a1.h[1] + (float)c1.h[1]);
    float p = fc_w[4 * q + 0] * h0 + fc_w[4 * q + 1] * h1
            + fc_w[4 * q + 2] * h2 + fc_w[4 * q + 3] * h3;
    p += __shfl_xor(p, 16);
    p += __shfl_xor(p, 32);
    if (lane < 16) out[b0 + col] = p + fc_b[0];
}

extern "C" void kernel_launch(void* const* d_in, const int* in_sizes, int n_in,
                              void* d_out, int out_size, void* d_ws, size_t ws_size,
                              hipStream_t stream)
{
    const float* x    = (const float*)d_in[0];
    const float* W_ih = (const float*)d_in[1];
    const float* W_hh = (const float*)d_in[2];
    const float* b_ih = (const float*)d_in[3];
    const float* b_hh = (const float*)d_in[4];
    const float* fc_w = (const float*)d_in[5];
    const float* fc_b = (const float*)d_in[6];
    float* out = (float*)d_out;

    dim3 grid(RNN_B / NE);   // 512 blocks x 64 threads
    dim3 block(64);
    rnn_mfma_kernel<<<grid, block, 0, stream>>>(x, W_ih, W_hh, b_ih, b_hh, fc_w, fc_b, out);
}